// Round 10
// baseline (146.586 us; speedup 1.0000x reference)
//
#include <hip/hip_runtime.h>

// ---------------------------------------------------------------------------
// Fused causal MHA:  out = attn(x@Wqkv+b) @ Wproj + bproj
// B=2, L=2048, D=1024, H=16, DH=64
// Device buffers may be f32 or bf16 (runtime-detected); bf16 MFMA internally.
// Softmax in exp2 space (Q pre-scaled by 0.125*log2e in the QKV epilogue).
// ---------------------------------------------------------------------------

typedef __bf16 bf16x8 __attribute__((ext_vector_type(8)));
typedef float  f32x4  __attribute__((ext_vector_type(4)));
typedef unsigned short bhalf;
typedef unsigned int   uint32;

#define B_  2
#define L_  2048
#define D_  1024
#define H_  16
#define DH_ 64

#define GPTR(p) ((const __attribute__((address_space(1))) void*)(p))
#define SPTR(p) ((__attribute__((address_space(3))) void*)(p))

static __device__ __forceinline__ float bf2f(bhalf u) {
    union { uint32 u; float f; } x; x.u = ((uint32)u) << 16; return x.f;
}
static __device__ __forceinline__ bhalf f2bf(float f) {
    union { float f; uint32 u; } x; x.f = f;
    uint32 r = x.u + 0x7FFFu + ((x.u >> 16) & 1u);   // RNE
    return (bhalf)(r >> 16);
}

// ---------------------------------------------------------------------------
__global__ void detect_dtype(const uint32* __restrict__ xw, int* __restrict__ flag) {
    int t = threadIdx.x;                     // 64 threads
    uint32 w = xw[t];
    uint32 e = (w >> 7) & 0xFFu;             // exponent of low-half bf16
    int g = (e < 0x6Fu || e > 0x84u) ? 1 : 0;
#pragma unroll
    for (int off = 32; off; off >>= 1) g += __shfl_xor(g, off);
    if (t == 0) *flag = (g > 16) ? 0 : 1;
}

// ---------------------------------------------------------------------------
__global__ void conv_bf16(const void* __restrict__ in, bhalf* __restrict__ out,
                          int n4, const int* __restrict__ flag) {
    const bool isb = (*flag != 0);
    for (int i = blockIdx.x * blockDim.x + threadIdx.x; i < n4;
         i += gridDim.x * blockDim.x) {
        if (isb) {
            ((uint2*)out)[i] = ((const uint2*)in)[i];
        } else {
            float4 v = ((const float4*)in)[i];
            uint2 o;
            o.x = (uint32)f2bf(v.x) | ((uint32)f2bf(v.y) << 16);
            o.y = (uint32)f2bf(v.z) | ((uint32)f2bf(v.w) << 16);
            ((uint2*)out)[i] = o;
        }
    }
}

// ---------------------------------------------------------------------------
__global__ void tr_conv(const void* __restrict__ in, bhalf* __restrict__ out,
                        int R, int C, const int* __restrict__ flag) {
    __shared__ bhalf t[32][33];
    const bool isb = (*flag != 0);
    int bx = blockIdx.x, by = blockIdx.y;
    int tx = threadIdx.x, ty = threadIdx.y;   // (32, 8)
#pragma unroll
    for (int i = 0; i < 32; i += 8) {
        size_t idx = (size_t)(by * 32 + ty + i) * C + bx * 32 + tx;
        t[ty + i][tx] = isb ? ((const bhalf*)in)[idx]
                            : f2bf(((const float*)in)[idx]);
    }
    __syncthreads();
#pragma unroll
    for (int i = 0; i < 32; i += 8)
        out[(size_t)(bx * 32 + ty + i) * R + by * 32 + tx] = t[tx][ty + i];
}

// ---------------------------------------------------------------------------
// QKV GEMM, phase-split schedule (m198/m201 recipe adapted):
// C[4096][3072] = A[4096][1024] @ Bt[3072][1024]^T + bias, scattered to
// Q (pre-scaled), K [B,H,L,DH], Vt [B,H,DH,L].
// BM=256, BN=192, BK=32; 8 waves (2Mx4N), per-wave 128x48 (8x3 frags).
// Grid 16x16 = 256 blocks = exactly 1/CU. LDS 56 KB (dbuf A 256x32, B 192x32).
// Per K-tile: 2 phases {stage-issue, ds_read subtile, lgkmcnt(0), setprio,
// 12 MFMA, barrier}; counted vmcnt(2) once per tile (never 0 in loop).
// Phase barriers are scheduling-only (both phases read the same buffer);
// buffer-overwrite safety comes from the end-of-tile barrier ordering.
// ---------------------------------------------------------------------------
__global__ __launch_bounds__(512, 2) void gemm_qkv256(
        const bhalf* __restrict__ A, const bhalf* __restrict__ Bt,
        const void* __restrict__ bias,
        bhalf* __restrict__ Qb, bhalf* __restrict__ Kb, bhalf* __restrict__ Vtb,
        int K, const int* __restrict__ flag) {
    __shared__ bhalf As[2][256 * 32];   // 2 x 16 KB
    __shared__ bhalf Bs[2][192 * 32];   // 2 x 12 KB
    const bool isb = (*flag != 0);
    const int tid = threadIdx.x;
    const int w = tid >> 6, lane = tid & 63;
    const int g = lane >> 4, cl = lane & 15;
    const int wr = w >> 2, wc = w & 3;            // 2 x 4 wave grid
    const int m0 = blockIdx.y * 256, n0 = blockIdx.x * 192;

    const bhalf* a0 = A  + (size_t)m0 * K;
    const bhalf* b0 = Bt + (size_t)n0 * K;

    f32x4 acc[8][3] = {};                          // 96 VGPRs

    // staging: chunk-permuted source (p holds logical chunk (p-row-(row>>2))&3),
    // linear LDS dest = wave-uniform base + lane*16B.
#define ST_A(BUF, KK, R) do {                                                 \
    int c = (R) * 512 + tid;                                                  \
    int row = c >> 2, p = c & 3;                                              \
    int gch = (p - row - (row >> 2)) & 3;                                     \
    __builtin_amdgcn_global_load_lds(                                         \
        GPTR(a0 + (size_t)row * K + (KK) + gch * 8),                          \
        SPTR(&As[BUF][((R) * 512 + (w << 6)) * 8]), 16, 0, 0);                \
} while (0)
#define ST_B0(BUF, KK) do {                                                   \
    int c = tid;                                                              \
    int row = c >> 2, p = c & 3;                                              \
    int gch = (p - row - (row >> 2)) & 3;                                     \
    __builtin_amdgcn_global_load_lds(                                         \
        GPTR(b0 + (size_t)row * K + (KK) + gch * 8),                          \
        SPTR(&Bs[BUF][(w << 6) * 8]), 16, 0, 0);                              \
} while (0)
#define ST_B1(BUF, KK) do {                                                   \
    if (tid < 256) {       /* wave-uniform: waves 0-3 only */                 \
        int c = 512 + tid;                                                    \
        int row = c >> 2, p = c & 3;                                          \
        int gch = (p - row - (row >> 2)) & 3;                                 \
        __builtin_amdgcn_global_load_lds(                                     \
            GPTR(b0 + (size_t)row * K + (KK) + gch * 8),                      \
            SPTR(&Bs[BUF][(512 + (w << 6)) * 8]), 16, 0, 0);                  \
    }                                                                         \
} while (0)

    const int NT = K >> 5;            // 32
    // prologue: tile 0 fully staged
    ST_A(0, 0, 0); ST_A(0, 0, 1); ST_B0(0, 0); ST_B1(0, 0);
    asm volatile("s_waitcnt vmcnt(0)" ::: "memory");
    __builtin_amdgcn_s_barrier();

    for (int t = 0; t < NT; ++t) {
        const int cur = t & 1;
        const int kn = ((t + 1 < NT) ? t + 1 : NT - 1) << 5;  // clamped tail
        bf16x8 af[4], bf[3];

        // ---------------- phase 0 (rows wr*128 + 0..63) ----------------
        ST_A(cur ^ 1, kn, 0);
        ST_B0(cur ^ 1, kn);
        // ledger: own tile-t loads (<=4) + 2 just issued -> wait to 2
        asm volatile("s_waitcnt vmcnt(2)" ::: "memory");
        __builtin_amdgcn_sched_barrier(0);
        __builtin_amdgcn_s_barrier();          // tile t resident block-wide
        __builtin_amdgcn_sched_barrier(0);
#pragma unroll
        for (int n = 0; n < 3; n++) {
            int rb = wc * 48 + n * 16 + cl;
            bf[n] = *(const bf16x8*)(&Bs[cur][rb * 32 +
                                     (((g + rb + (rb >> 2)) & 3) * 8)]);
        }
#pragma unroll
        for (int m = 0; m < 4; m++) {
            int ra = wr * 128 + m * 16 + cl;
            af[m] = *(const bf16x8*)(&As[cur][ra * 32 +
                                     (((g + ra + (ra >> 2)) & 3) * 8)]);
        }
        asm volatile("s_waitcnt lgkmcnt(0)" ::: "memory");
        __builtin_amdgcn_sched_barrier(0);
        __builtin_amdgcn_s_setprio(1);
#pragma unroll
        for (int m = 0; m < 4; m++)
#pragma unroll
            for (int n = 0; n < 3; n++)
                acc[m][n] = __builtin_amdgcn_mfma_f32_16x16x32_bf16(
                    af[m], bf[n], acc[m][n], 0, 0, 0);
        __builtin_amdgcn_s_setprio(0);
        __builtin_amdgcn_s_barrier();          // phase boundary (scheduling)

        // ---------------- phase 1 (rows wr*128 + 64..127) ----------------
        ST_A(cur ^ 1, kn, 1);
        ST_B1(cur ^ 1, kn);
#pragma unroll
        for (int m = 0; m < 4; m++) {
            int ra = wr * 128 + 64 + m * 16 + cl;
            af[m] = *(const bf16x8*)(&As[cur][ra * 32 +
                                     (((g + ra + (ra >> 2)) & 3) * 8)]);
        }
        asm volatile("s_waitcnt lgkmcnt(0)" ::: "memory");
        __builtin_amdgcn_sched_barrier(0);
        __builtin_amdgcn_s_setprio(1);
#pragma unroll
        for (int m = 0; m < 4; m++)
#pragma unroll
            for (int n = 0; n < 3; n++)
                acc[4 + m][n] = __builtin_amdgcn_mfma_f32_16x16x32_bf16(
                    af[m], bf[n], acc[4 + m][n], 0, 0, 0);
        __builtin_amdgcn_s_setprio(0);
        __builtin_amdgcn_s_barrier();          // end of tile t
    }
#undef ST_A
#undef ST_B0
#undef ST_B1

    // epilogue: C/D layout col = lane&15, row = (lane>>4)*4 + reg; QKV scatter
#pragma unroll
    for (int mi = 0; mi < 8; mi++) {
#pragma unroll
        for (int n = 0; n < 3; n++) {
            int nn = n0 + wc * 48 + n * 16 + cl;
            float bv = isb ? bf2f(((const bhalf*)bias)[nn])
                           : ((const float*)bias)[nn];
#pragma unroll
            for (int r = 0; r < 4; r++) {
                int mm = m0 + wr * 128 + (mi >> 2) * 64 + (mi & 3) * 16 + g * 4 + r;
                float v = acc[mi][n][r] + bv;
                int b = mm >> 11, l = mm & 2047;
                int three = nn >> 10, rem = nn & 1023;
                int h = rem >> 6, dh = rem & 63;
                size_t bh = (size_t)(b * 16 + h);
                if (three == 0) {
                    Qb[(bh * 2048 + l) * 64 + dh] = f2bf(v * 0.18033688f);
                } else if (three == 1) {
                    Kb [(bh * 2048 + l) * 64 + dh] = f2bf(v);
                } else {
                    Vtb[(bh * 64 + dh) * 2048 + l] = f2bf(v);
                }
            }
        }
    }
}

// ---------------------------------------------------------------------------
// GEMM  C[M][N] = A[M][K] @ Bt[N][K]^T + bias[N]   (output projection)
// 128x128 tile, BK=32, 4 waves; 3-buffer LDS, counted vmcnt(4) + s_barrier.
// ---------------------------------------------------------------------------
#define GSTAGE(BUF, KK) do {                                                  \
    int kko = (KK);                                                           \
    int bufv = (BUF);                                                         \
    _Pragma("unroll")                                                         \
    for (int r = 0; r < 2; r++) {                                             \
        int c = r * 256 + tid;                                                \
        int row = c >> 2, p = c & 3;                                          \
        int gch = (p - row - (row >> 2)) & 3;                                 \
        __builtin_amdgcn_global_load_lds(                                     \
            GPTR(a0 + (size_t)row * K + kko + gch * 8),                       \
            SPTR(As + bufv * 4096 + (r * 256 + w * 64) * 8), 16, 0, 0);       \
        __builtin_amdgcn_global_load_lds(                                     \
            GPTR(b0 + (size_t)row * K + kko + gch * 8),                       \
            SPTR(Bs + bufv * 4096 + (r * 256 + w * 64) * 8), 16, 0, 0);       \
    }                                                                         \
} while (0)

__global__ __launch_bounds__(256) void gemm_proj(
        const bhalf* __restrict__ A, const bhalf* __restrict__ Bt,
        const void* __restrict__ bias, void* __restrict__ C0,
        int M, int N, int K, const int* __restrict__ flag) {
    __shared__ bhalf As[3 * 128 * 32];
    __shared__ bhalf Bs[3 * 128 * 32];
    const bool isb = (*flag != 0);
    const int tid  = threadIdx.x;
    const int w    = tid >> 6, lane = tid & 63;
    const int g    = lane >> 4, cl = lane & 15;
    const int m0   = blockIdx.y * 128, n0 = blockIdx.x * 128;
    const int wr   = (w >> 1) * 64, wc = (w & 1) * 64;

    f32x4 acc[4][4] = {};

    const bhalf* a0 = A  + (size_t)m0 * K;
    const bhalf* b0 = Bt + (size_t)n0 * K;

    const int nk = K >> 5;
    GSTAGE(0, 0);
    GSTAGE(1, 32);

    for (int t = 0; t < nk; ++t) {
        asm volatile("s_waitcnt vmcnt(4)" ::: "memory");
        __builtin_amdgcn_sched_barrier(0);
        __builtin_amdgcn_s_barrier();
        __builtin_amdgcn_sched_barrier(0);

        int tp = t + 2 < nk ? t + 2 : nk - 1;
        GSTAGE((t + 2) % 3, tp << 5);

        int cur = t % 3;
        bf16x8 af[4], bf4[4];
#pragma unroll
        for (int i = 0; i < 4; i++) {
            int ra = wr + i * 16 + cl;
            af[i]  = *(const bf16x8*)(As + cur * 4096 + ra * 32 +
                                      (((g + ra + (ra >> 2)) & 3) * 8));
            int rb = wc + i * 16 + cl;
            bf4[i] = *(const bf16x8*)(Bs + cur * 4096 + rb * 32 +
                                      (((g + rb + (rb >> 2)) & 3) * 8));
        }
        __builtin_amdgcn_s_setprio(1);
#pragma unroll
        for (int i = 0; i < 4; i++)
#pragma unroll
            for (int j = 0; j < 4; j++)
                acc[i][j] = __builtin_amdgcn_mfma_f32_16x16x32_bf16(
                    af[i], bf4[j], acc[i][j], 0, 0, 0);
        __builtin_amdgcn_s_setprio(0);
    }

#pragma unroll
    for (int i = 0; i < 4; i++) {
#pragma unroll
        for (int j = 0; j < 4; j++) {
            int nn = n0 + wc + j * 16 + cl;
            float bv = isb ? bf2f(((const bhalf*)bias)[nn])
                           : ((const float*)bias)[nn];
#pragma unroll
            for (int r = 0; r < 4; r++) {
                int mm = m0 + wr + i * 16 + g * 4 + r;
                float v = acc[i][j][r] + bv;
                if (isb) ((bhalf*)C0)[(size_t)mm * N + nn] = f2bf(v);
                else     ((float*)C0)[(size_t)mm * N + nn] = v;
            }
        }
    }
}

// ---------------------------------------------------------------------------
// Causal flash attention (unchanged from round 8): swapped-QK^T, in-register
// exp2 softmax, paired q-tiles (17 units/block), dbuf global_load_lds.
// ---------------------------------------------------------------------------
#define STAGE(BUF, KT) do {                                                   \
    int ktv = (KT);                                                           \
    _Pragma("unroll")                                                         \
    for (int r = 0; r < 4; r++) {                                             \
        int c = r * 256 + tid;                                                \
        int row = c >> 3, p = c & 7;                                          \
        int fsw = (row & 3) | (((row >> 3) & 1) << 2);                        \
        __builtin_amdgcn_global_load_lds(                                     \
            GPTR(Kp + (size_t)(ktv * 128 + row) * 64 + (p ^ fsw) * 8),        \
            SPTR(Ks[BUF] + (r * 256 + w * 64) * 8), 16, 0, 0);                \
    }                                                                         \
    _Pragma("unroll")                                                         \
    for (int r = 0; r < 4; r++) {                                             \
        int c = r * 256 + tid;                                                \
        int row = c >> 4, p = c & 15;                                         \
        __builtin_amdgcn_global_load_lds(                                     \
            GPTR(Vt + (size_t)row * L_ + ktv * 128 + (p ^ (row & 15)) * 8),   \
            SPTR(Vs[BUF] + (r * 256 + w * 64) * 8), 16, 0, 0);                \
    }                                                                         \
} while (0)

#define ATTN_TILE(BUF, KT, QF, QLANE, MVAR, LVAR, OACC, MASK) do {            \
    f32x4 p8[8] = {};                                                         \
    _Pragma("unroll")                                                         \
    for (int s = 0; s < 2; s++) {                                             \
        bf16x8 kf[8];                                                         \
        _Pragma("unroll")                                                     \
        for (int j = 0; j < 8; j++) {                                         \
            int row = (j >> 1) * 32 + (cl >> 2) * 8 + (j & 1) * 4 + (cl & 3); \
            int fsw = (row & 3) | (((row >> 3) & 1) << 2);                    \
            int ch = s * 4 + g;                                               \
            kf[j] = *(const bf16x8*)(Ks[BUF] + row * 64 + ((ch ^ fsw) * 8));  \
        }                                                                     \
        __builtin_amdgcn_s_setprio(1);                                        \
        _Pragma("unroll")                                                     \
        for (int j = 0; j < 8; j++)                                           \
            p8[j] = __builtin_amdgcn_mfma_f32_16x16x32_bf16(                  \
                kf[j], QF[s], p8[j], 0, 0, 0);                                \
        __builtin_amdgcn_s_setprio(0);                                        \
    }                                                                         \
    float mx0 = -__builtin_inff(), mx1 = -__builtin_inff();                   \
    float mx2 = -__builtin_inff(), mx3 = -__builtin_inff();                   \
    _Pragma("unroll")                                                         \
    for (int j = 0; j < 8; j++) {                                             \
        float v0 = p8[j][0], v1 = p8[j][1], v2 = p8[j][2], v3 = p8[j][3];     \
        if (MASK) {                                                           \
            int ka = (KT) * 128 + (j >> 1) * 32 + g * 8 + ((j & 1) << 2);     \
            v0 = (ka + 0 > (QLANE)) ? -__builtin_inff() : v0;                 \
            v1 = (ka + 1 > (QLANE)) ? -__builtin_inff() : v1;                 \
            v2 = (ka + 2 > (QLANE)) ? -__builtin_inff() : v2;                 \
            v3 = (ka + 3 > (QLANE)) ? -__builtin_inff() : v3;                 \
            p8[j][0] = v0; p8[j][1] = v1; p8[j][2] = v2; p8[j][3] = v3;       \
        }                                                                     \
        mx0 = fmaxf(mx0, v0); mx1 = fmaxf(mx1, v1);                           \
        mx2 = fmaxf(mx2, v2); mx3 = fmaxf(mx3, v3);                           \
    }                                                                         \
    float mx = fmaxf(fmaxf(mx0, mx1), fmaxf(mx2, mx3));                       \
    mx = fmaxf(mx, __shfl_xor(mx, 16));                                       \
    mx = fmaxf(mx, __shfl_xor(mx, 32));                                       \
    if (!__all(mx - MVAR <= 8.f)) {                                           \
        float mnew = fmaxf(MVAR, mx);                                         \
        float alpha = __builtin_amdgcn_exp2f(MVAR - mnew);                    \
        MVAR = mnew;                                                          \
        LVAR *= alpha;                                                        \
        _Pragma("unroll")                                                     \
        for (int r = 0; r < 4; r++) {                                         \
            float ar = __shfl(alpha, g * 4 + r);                              \
            _Pragma("unroll")                                                 \
            for (int dj = 0; dj < 4; dj++) OACC[dj][r] *= ar;                 \
        }                                                                     \
    }                                                                         \
    float s0 = 0.f, s1 = 0.f, s2 = 0.f, s3 = 0.f;                             \
    _Pragma("unroll")                                                         \
    for (int j = 0; j < 8; j++) {                                             \
        float e0 = __builtin_amdgcn_exp2f(p8[j][0] - MVAR);                   \
        float e1 = __builtin_amdgcn_exp2f(p8[j][1] - MVAR);                   \
        float e2 = __builtin_amdgcn_exp2f(p8[j][2] - MVAR);                   \
        float e3 = __builtin_amdgcn_exp2f(p8[j][3] - MVAR);                   \
        p8[j][0] = e0; p8[j][1] = e1; p8[j][2] = e2; p8[j][3] = e3;           \
        s0 += e0; s1 += e1; s2 += e2; s3 += e3;                               \
    }                                                                         \
    float ls = (s0 + s1) + (s2 + s3);                                         \
    ls += __shfl_xor(ls, 16);                                                 \
    ls += __shfl_xor(ls, 32);                                                 \
    LVAR += ls;                                                               \
    _Pragma("unroll")                                                         \
    for (int ks = 0; ks < 4; ks++) {                                          \
        bf16x8 pf;                                                            \
        _Pragma("unroll")                                                     \
        for (int e = 0; e < 8; e++)                                           \
            pf[e] = (__bf16)p8[2 * ks + (e >> 2)][e & 3];                     \
        bf16x8 vf[4];                                                         \
        _Pragma("unroll")                                                     \
        for (int dj = 0; dj < 4; dj++) {                                      \
            int vrow = dj * 16 + cl;                                          \
            int ch = ks * 4 + g;                                              \
            vf[dj] = *(const bf16x8*)(Vs[BUF] + vrow * 128 + ((ch ^ (vrow & 15)) * 8)); \
        }                                                                     \
        __builtin_amdgcn_s_setprio(1);                                        \
        _Pragma("unroll")                                                     \
        for (int dj = 0; dj < 4; dj++)                                        \
            OACC[dj] = __builtin_amdgcn_mfma_f32_16x16x32_bf16(               \
                pf, vf[dj], OACC[dj], 0, 0, 0);                               \
        __builtin_amdgcn_s_setprio(0);                                        \
    }                                                                         \
} while (0)

__global__ __launch_bounds__(256, 2) void attn_fwd(
        const bhalf* __restrict__ Qb, const bhalf* __restrict__ Kb,
        const bhalf* __restrict__ Vtb, bhalf* __restrict__ Ob) {
    __shared__ bhalf Ks[2][128 * 64];
    __shared__ bhalf Vs[2][64 * 128];

    const int bid  = blockIdx.x;
    const int xcd  = bid & 7, slot = bid >> 3;
    const int bx   = slot & 15;
    const int bh   = xcd + 8 * (slot >> 4);
    const int qbA  = 31 - bx;
    const int qbB  = bx;

    const int tid = threadIdx.x;
    const int w = tid >> 6, lane = tid & 63;
    const int g = lane >> 4, cl = lane & 15;

    const bhalf* Q  = Qb  + (size_t)bh * L_ * DH_;
    const bhalf* Kp = Kb  + (size_t)bh * L_ * DH_;
    const bhalf* Vt = Vtb + (size_t)bh * DH_ * L_;

    const int q0A = qbA * 64 + w * 16, qlA = q0A + cl;
    const int q0B = qbB * 64 + w * 16, qlB = q0B + cl;

    bf16x8 qfA[2], qfB[2];
#pragma unroll
    for (int s = 0; s < 2; s++) {
        qfA[s] = *(const bf16x8*)(Q + (size_t)(q0A + cl) * 64 + s * 32 + g * 8);
        qfB[s] = *(const bf16x8*)(Q + (size_t)(q0B + cl) * 64 + s * 32 + g * 8);
    }

    f32x4 oA[4] = {}, oB[4] = {};
    float mA = -__builtin_inff(), lA = 0.f;
    float mB = -__builtin_inff(), lB = 0.f;

    const int nktA = (qbA >> 1) + 1;
    const int nktB = (qbB >> 1) + 1;

    STAGE(0, 0);
    __syncthreads();

    for (int kt = 0; kt < nktA; ++kt) {
        int cur = kt & 1;
        if (kt + 1 < nktA) STAGE(cur ^ 1, kt + 1);
        if (kt < nktB) {
            ATTN_TILE(cur, kt, qfB, qlB, mB, lB, oB, (kt == nktB - 1));
        }
        ATTN_TILE(cur, kt, qfA, qlA, mA, lA, oA, (kt == nktA - 1));
        __syncthreads();
    }

    const int b = bh >> 4, h = bh & 15;
#pragma unroll
    for (int r = 0; r < 4; r++) {
        float lrA = __shfl(lA, g * 4 + r);
        float lrB = __shfl(lB, g * 4 + r);
        float invA = 1.f / (lrA + 1e-6f);
        float invB = 1.f / (lrB + 1e-6f);
        int qrA = q0A + g * 4 + r, qrB = q0B + g * 4 + r;
#pragma unroll
        for (int dj = 0; dj < 4; dj++) {
            Ob[((size_t)b * L_ + qrA) * D_ + h * 64 + dj * 16 + cl] =
                f2bf(oA[dj][r] * invA);
            Ob[((size_t)b * L_ + qrB) * D_ + h * 64 + dj * 16 + cl] =
                f2bf(oB[dj][r] * invB);
        }
    }
}

// ---------------------------------------------------------------------------
extern "C" void kernel_launch(void* const* d_in, const int* in_sizes, int n_in,
                              void* d_out, int out_size, void* d_ws, size_t ws_size,
                              hipStream_t stream) {
    const void* x     = d_in[0];   // [B,L,D]     f32 or bf16
    const void* Wqkv  = d_in[1];   // [D, 3D]
    const void* bqkv  = d_in[2];   // [3D]
    const void* Wproj = d_in[3];   // [D, D]
    const void* bproj = d_in[4];   // [D]

    char* ws = (char*)d_ws;
    const size_t SZ_FLG = 256;
    const size_t SZ_WQT = (size_t)3 * D_ * D_ * 2;        //  6 MB
    const size_t SZ_WPT = (size_t)D_ * D_ * 2;            //  2 MB
    const size_t SZ_X   = (size_t)B_ * L_ * D_ * 2;       //  8 MB
    const size_t SZ_BUF = (size_t)B_ * H_ * L_ * DH_ * 2; //  8 MB each

    int*   flag = (int*)ws;
    bhalf* Wq_t = (bhalf*)(ws + SZ_FLG);
    bhalf* Wp_t = (bhalf*)(ws + SZ_FLG + SZ_WQT);
    bhalf* Xb   = (bhalf*)(ws + SZ_FLG + SZ_WQT + SZ_WPT);
    bhalf* Qbuf = (bhalf*)(ws + SZ_FLG + SZ_WQT + SZ_WPT + SZ_X);
    bhalf* Kbuf = (bhalf*)(ws + SZ_FLG + SZ_WQT + SZ_WPT + SZ_X + SZ_BUF);
    bhalf* Vtbf = (bhalf*)(ws + SZ_FLG + SZ_WQT + SZ_WPT + SZ_X + 2 * SZ_BUF);
    bhalf* Obuf = (bhalf*)(ws + SZ_FLG + SZ_WQT + SZ_WPT + SZ_X + 3 * SZ_BUF);

    const int M = B_ * L_;   // 4096

    // 0. runtime dtype detection
    detect_dtype<<<1, 64, 0, stream>>>((const uint32*)x, flag);

    // 1. canonicalize inputs to bf16 workspace
    conv_bf16<<<2048, 256, 0, stream>>>(x, Xb, (B_ * L_ * D_) / 4, flag);
    tr_conv<<<dim3(3 * D_ / 32, D_ / 32), dim3(32, 8), 0, stream>>>(
        Wqkv, Wq_t, D_, 3 * D_, flag);
    tr_conv<<<dim3(D_ / 32, D_ / 32), dim3(32, 8), 0, stream>>>(
        Wproj, Wp_t, D_, D_, flag);

    // 2. QKV projection (phase-split 256x192 kernel, grid 16x16 = 1 block/CU)
    gemm_qkv256<<<dim3(3 * D_ / 192, M / 256), 512, 0, stream>>>(
        Xb, Wq_t, bqkv, Qbuf, Kbuf, Vtbf, D_, flag);

    // 3. causal flash attention -> Obuf [B,L,D] bf16
    attn_fwd<<<dim3(512), 256, 0, stream>>>(Qbuf, Kbuf, Vtbf, Obuf);

    // 4. output projection -> d_out
    gemm_proj<<<dim3(D_ / 128, M / 128), 256, 0, stream>>>(
        Obuf, Wp_t, bproj, d_out, M, D_, D_, flag);
}

// Round 11
// 146.253 us; speedup vs baseline: 1.0023x; 1.0023x over previous
//
#include <hip/hip_runtime.h>

// ---------------------------------------------------------------------------
// Fused causal MHA:  out = attn(x@Wqkv+b) @ Wproj + bproj
// B=2, L=2048, D=1024, H=16, DH=64
// Device buffers may be f32 or bf16 (runtime-detected); bf16 MFMA internally.
// Softmax in exp2 space (Q pre-scaled by 0.125*log2e in the QKV epilogue).
// ---------------------------------------------------------------------------

typedef __bf16 bf16x8 __attribute__((ext_vector_type(8)));
typedef float  f32x4  __attribute__((ext_vector_type(4)));
typedef unsigned short bhalf;
typedef unsigned int   uint32;

#define B_  2
#define L_  2048
#define D_  1024
#define H_  16
#define DH_ 64

#define GPTR(p) ((const __attribute__((address_space(1))) void*)(p))
#define SPTR(p) ((__attribute__((address_space(3))) void*)(p))

static __device__ __forceinline__ float bf2f(bhalf u) {
    union { uint32 u; float f; } x; x.u = ((uint32)u) << 16; return x.f;
}
static __device__ __forceinline__ bhalf f2bf(float f) {
    union { float f; uint32 u; } x; x.f = f;
    uint32 r = x.u + 0x7FFFu + ((x.u >> 16) & 1u);   // RNE
    return (bhalf)(r >> 16);
}

// ---------------------------------------------------------------------------
__global__ void detect_dtype(const uint32* __restrict__ xw, int* __restrict__ flag) {
    int t = threadIdx.x;                     // 64 threads
    uint32 w = xw[t];
    uint32 e = (w >> 7) & 0xFFu;             // exponent of low-half bf16
    int g = (e < 0x6Fu || e > 0x84u) ? 1 : 0;
#pragma unroll
    for (int off = 32; off; off >>= 1) g += __shfl_xor(g, off);
    if (t == 0) *flag = (g > 16) ? 0 : 1;
}

// ---------------------------------------------------------------------------
__global__ void conv_bf16(const void* __restrict__ in, bhalf* __restrict__ out,
                          int n4, const int* __restrict__ flag) {
    const bool isb = (*flag != 0);
    for (int i = blockIdx.x * blockDim.x + threadIdx.x; i < n4;
         i += gridDim.x * blockDim.x) {
        if (isb) {
            ((uint2*)out)[i] = ((const uint2*)in)[i];
        } else {
            float4 v = ((const float4*)in)[i];
            uint2 o;
            o.x = (uint32)f2bf(v.x) | ((uint32)f2bf(v.y) << 16);
            o.y = (uint32)f2bf(v.z) | ((uint32)f2bf(v.w) << 16);
            ((uint2*)out)[i] = o;
        }
    }
}

// ---------------------------------------------------------------------------
__global__ void tr_conv(const void* __restrict__ in, bhalf* __restrict__ out,
                        int R, int C, const int* __restrict__ flag) {
    __shared__ bhalf t[32][33];
    const bool isb = (*flag != 0);
    int bx = blockIdx.x, by = blockIdx.y;
    int tx = threadIdx.x, ty = threadIdx.y;   // (32, 8)
#pragma unroll
    for (int i = 0; i < 32; i += 8) {
        size_t idx = (size_t)(by * 32 + ty + i) * C + bx * 32 + tx;
        t[ty + i][tx] = isb ? ((const bhalf*)in)[idx]
                            : f2bf(((const float*)in)[idx]);
    }
    __syncthreads();
#pragma unroll
    for (int i = 0; i < 32; i += 8)
        out[(size_t)(bx * 32 + ty + i) * R + by * 32 + tx] = t[tx][ty + i];
}

// ---------------------------------------------------------------------------
// QKV GEMM, phase-split schedule (m198/m201 recipe adapted):
// C[4096][3072] = A[4096][1024] @ Bt[3072][1024]^T + bias, scattered to
// Q (pre-scaled), K [B,H,L,DH], Vt [B,H,DH,L].
// BM=256, BN=192, BK=32; 8 waves (2Mx4N), per-wave 128x48 (8x3 frags).
// Grid 16x16 = 256 blocks = exactly 1/CU. LDS 56 KB (dbuf A 256x32, B 192x32).
// Per K-tile: 2 phases {stage-issue, ds_read subtile, lgkmcnt(0), setprio,
// 12 MFMA, barrier}; counted vmcnt(2) once per tile (never 0 in loop).
// Phase barriers are scheduling-only (both phases read the same buffer);
// buffer-overwrite safety comes from the end-of-tile barrier ordering.
// ---------------------------------------------------------------------------
__global__ __launch_bounds__(512, 2) void gemm_qkv256(
        const bhalf* __restrict__ A, const bhalf* __restrict__ Bt,
        const void* __restrict__ bias,
        bhalf* __restrict__ Qb, bhalf* __restrict__ Kb, bhalf* __restrict__ Vtb,
        int K, const int* __restrict__ flag) {
    __shared__ bhalf As[2][256 * 32];   // 2 x 16 KB
    __shared__ bhalf Bs[2][192 * 32];   // 2 x 12 KB
    const bool isb = (*flag != 0);
    const int tid = threadIdx.x;
    const int w = tid >> 6, lane = tid & 63;
    const int g = lane >> 4, cl = lane & 15;
    const int wr = w >> 2, wc = w & 3;            // 2 x 4 wave grid
    const int m0 = blockIdx.y * 256, n0 = blockIdx.x * 192;

    const bhalf* a0 = A  + (size_t)m0 * K;
    const bhalf* b0 = Bt + (size_t)n0 * K;

    f32x4 acc[8][3] = {};                          // 96 VGPRs

    // staging: chunk-permuted source (p holds logical chunk (p-row-(row>>2))&3),
    // linear LDS dest = wave-uniform base + lane*16B.
#define ST_A(BUF, KK, R) do {                                                 \
    int c = (R) * 512 + tid;                                                  \
    int row = c >> 2, p = c & 3;                                              \
    int gch = (p - row - (row >> 2)) & 3;                                     \
    __builtin_amdgcn_global_load_lds(                                         \
        GPTR(a0 + (size_t)row * K + (KK) + gch * 8),                          \
        SPTR(&As[BUF][((R) * 512 + (w << 6)) * 8]), 16, 0, 0);                \
} while (0)
#define ST_B0(BUF, KK) do {                                                   \
    int c = tid;                                                              \
    int row = c >> 2, p = c & 3;                                              \
    int gch = (p - row - (row >> 2)) & 3;                                     \
    __builtin_amdgcn_global_load_lds(                                         \
        GPTR(b0 + (size_t)row * K + (KK) + gch * 8),                          \
        SPTR(&Bs[BUF][(w << 6) * 8]), 16, 0, 0);                              \
} while (0)
#define ST_B1(BUF, KK) do {                                                   \
    if (tid < 256) {       /* wave-uniform: waves 0-3 only */                 \
        int c = 512 + tid;                                                    \
        int row = c >> 2, p = c & 3;                                          \
        int gch = (p - row - (row >> 2)) & 3;                                 \
        __builtin_amdgcn_global_load_lds(                                     \
            GPTR(b0 + (size_t)row * K + (KK) + gch * 8),                      \
            SPTR(&Bs[BUF][(512 + (w << 6)) * 8]), 16, 0, 0);                  \
    }                                                                         \
} while (0)

    const int NT = K >> 5;            // 32
    // prologue: tile 0 fully staged
    ST_A(0, 0, 0); ST_A(0, 0, 1); ST_B0(0, 0); ST_B1(0, 0);
    asm volatile("s_waitcnt vmcnt(0)" ::: "memory");
    __builtin_amdgcn_s_barrier();

    for (int t = 0; t < NT; ++t) {
        const int cur = t & 1;
        const int kn = ((t + 1 < NT) ? t + 1 : NT - 1) << 5;  // clamped tail
        bf16x8 af[4], bf[3];

        // ---------------- phase 0 (rows wr*128 + 0..63) ----------------
        ST_A(cur ^ 1, kn, 0);
        ST_B0(cur ^ 1, kn);
        // ledger: own tile-t loads (<=4) + 2 just issued -> wait to 2
        asm volatile("s_waitcnt vmcnt(2)" ::: "memory");
        __builtin_amdgcn_sched_barrier(0);
        __builtin_amdgcn_s_barrier();          // tile t resident block-wide
        __builtin_amdgcn_sched_barrier(0);
#pragma unroll
        for (int n = 0; n < 3; n++) {
            int rb = wc * 48 + n * 16 + cl;
            bf[n] = *(const bf16x8*)(&Bs[cur][rb * 32 +
                                     (((g + rb + (rb >> 2)) & 3) * 8)]);
        }
#pragma unroll
        for (int m = 0; m < 4; m++) {
            int ra = wr * 128 + m * 16 + cl;
            af[m] = *(const bf16x8*)(&As[cur][ra * 32 +
                                     (((g + ra + (ra >> 2)) & 3) * 8)]);
        }
        asm volatile("s_waitcnt lgkmcnt(0)" ::: "memory");
        __builtin_amdgcn_sched_barrier(0);
        __builtin_amdgcn_s_setprio(1);
#pragma unroll
        for (int m = 0; m < 4; m++)
#pragma unroll
            for (int n = 0; n < 3; n++)
                acc[m][n] = __builtin_amdgcn_mfma_f32_16x16x32_bf16(
                    af[m], bf[n], acc[m][n], 0, 0, 0);
        __builtin_amdgcn_s_setprio(0);
        __builtin_amdgcn_s_barrier();          // phase boundary (scheduling)

        // ---------------- phase 1 (rows wr*128 + 64..127) ----------------
        ST_A(cur ^ 1, kn, 1);
        ST_B1(cur ^ 1, kn);
#pragma unroll
        for (int m = 0; m < 4; m++) {
            int ra = wr * 128 + 64 + m * 16 + cl;
            af[m] = *(const bf16x8*)(&As[cur][ra * 32 +
                                     (((g + ra + (ra >> 2)) & 3) * 8)]);
        }
        asm volatile("s_waitcnt lgkmcnt(0)" ::: "memory");
        __builtin_amdgcn_sched_barrier(0);
        __builtin_amdgcn_s_setprio(1);
#pragma unroll
        for (int m = 0; m < 4; m++)
#pragma unroll
            for (int n = 0; n < 3; n++)
                acc[4 + m][n] = __builtin_amdgcn_mfma_f32_16x16x32_bf16(
                    af[m], bf[n], acc[4 + m][n], 0, 0, 0);
        __builtin_amdgcn_s_setprio(0);
        __builtin_amdgcn_s_barrier();          // end of tile t
    }
#undef ST_A
#undef ST_B0
#undef ST_B1

    // epilogue: C/D layout col = lane&15, row = (lane>>4)*4 + reg; QKV scatter
#pragma unroll
    for (int mi = 0; mi < 8; mi++) {
#pragma unroll
        for (int n = 0; n < 3; n++) {
            int nn = n0 + wc * 48 + n * 16 + cl;
            float bv = isb ? bf2f(((const bhalf*)bias)[nn])
                           : ((const float*)bias)[nn];
#pragma unroll
            for (int r = 0; r < 4; r++) {
                int mm = m0 + wr * 128 + (mi >> 2) * 64 + (mi & 3) * 16 + g * 4 + r;
                float v = acc[mi][n][r] + bv;
                int b = mm >> 11, l = mm & 2047;
                int three = nn >> 10, rem = nn & 1023;
                int h = rem >> 6, dh = rem & 63;
                size_t bh = (size_t)(b * 16 + h);
                if (three == 0) {
                    Qb[(bh * 2048 + l) * 64 + dh] = f2bf(v * 0.18033688f);
                } else if (three == 1) {
                    Kb [(bh * 2048 + l) * 64 + dh] = f2bf(v);
                } else {
                    Vtb[(bh * 64 + dh) * 2048 + l] = f2bf(v);
                }
            }
        }
    }
}

// ---------------------------------------------------------------------------
// GEMM  C[M][N] = A[M][K] @ Bt[N][K]^T + bias[N]   (output projection)
// 128x128 tile, BK=32, 4 waves; 3-buffer LDS, counted vmcnt(4) + s_barrier.
// ---------------------------------------------------------------------------
#define GSTAGE(BUF, KK) do {                                                  \
    int kko = (KK);                                                           \
    int bufv = (BUF);                                                         \
    _Pragma("unroll")                                                         \
    for (int r = 0; r < 2; r++) {                                             \
        int c = r * 256 + tid;                                                \
        int row = c >> 2, p = c & 3;                                          \
        int gch = (p - row - (row >> 2)) & 3;                                 \
        __builtin_amdgcn_global_load_lds(                                     \
            GPTR(a0 + (size_t)row * K + kko + gch * 8),                       \
            SPTR(As + bufv * 4096 + (r * 256 + w * 64) * 8), 16, 0, 0);       \
        __builtin_amdgcn_global_load_lds(                                     \
            GPTR(b0 + (size_t)row * K + kko + gch * 8),                       \
            SPTR(Bs + bufv * 4096 + (r * 256 + w * 64) * 8), 16, 0, 0);       \
    }                                                                         \
} while (0)

__global__ __launch_bounds__(256) void gemm_proj(
        const bhalf* __restrict__ A, const bhalf* __restrict__ Bt,
        const void* __restrict__ bias, void* __restrict__ C0,
        int M, int N, int K, const int* __restrict__ flag) {
    __shared__ bhalf As[3 * 128 * 32];
    __shared__ bhalf Bs[3 * 128 * 32];
    const bool isb = (*flag != 0);
    const int tid  = threadIdx.x;
    const int w    = tid >> 6, lane = tid & 63;
    const int g    = lane >> 4, cl = lane & 15;
    const int m0   = blockIdx.y * 128, n0 = blockIdx.x * 128;
    const int wr   = (w >> 1) * 64, wc = (w & 1) * 64;

    f32x4 acc[4][4] = {};

    const bhalf* a0 = A  + (size_t)m0 * K;
    const bhalf* b0 = Bt + (size_t)n0 * K;

    const int nk = K >> 5;
    GSTAGE(0, 0);
    GSTAGE(1, 32);

    for (int t = 0; t < nk; ++t) {
        asm volatile("s_waitcnt vmcnt(4)" ::: "memory");
        __builtin_amdgcn_sched_barrier(0);
        __builtin_amdgcn_s_barrier();
        __builtin_amdgcn_sched_barrier(0);

        int tp = t + 2 < nk ? t + 2 : nk - 1;
        GSTAGE((t + 2) % 3, tp << 5);

        int cur = t % 3;
        bf16x8 af[4], bf4[4];
#pragma unroll
        for (int i = 0; i < 4; i++) {
            int ra = wr + i * 16 + cl;
            af[i]  = *(const bf16x8*)(As + cur * 4096 + ra * 32 +
                                      (((g + ra + (ra >> 2)) & 3) * 8));
            int rb = wc + i * 16 + cl;
            bf4[i] = *(const bf16x8*)(Bs + cur * 4096 + rb * 32 +
                                      (((g + rb + (rb >> 2)) & 3) * 8));
        }
        __builtin_amdgcn_s_setprio(1);
#pragma unroll
        for (int i = 0; i < 4; i++)
#pragma unroll
            for (int j = 0; j < 4; j++)
                acc[i][j] = __builtin_amdgcn_mfma_f32_16x16x32_bf16(
                    af[i], bf4[j], acc[i][j], 0, 0, 0);
        __builtin_amdgcn_s_setprio(0);
    }

#pragma unroll
    for (int i = 0; i < 4; i++) {
#pragma unroll
        for (int j = 0; j < 4; j++) {
            int nn = n0 + wc + j * 16 + cl;
            float bv = isb ? bf2f(((const bhalf*)bias)[nn])
                           : ((const float*)bias)[nn];
#pragma unroll
            for (int r = 0; r < 4; r++) {
                int mm = m0 + wr + i * 16 + g * 4 + r;
                float v = acc[i][j][r] + bv;
                if (isb) ((bhalf*)C0)[(size_t)mm * N + nn] = f2bf(v);
                else     ((float*)C0)[(size_t)mm * N + nn] = v;
            }
        }
    }
}

// ---------------------------------------------------------------------------
// Causal flash attention (unchanged from round 8): swapped-QK^T, in-register
// exp2 softmax, paired q-tiles (17 units/block), dbuf global_load_lds.
// ---------------------------------------------------------------------------
#define STAGE(BUF, KT) do {                                                   \
    int ktv = (KT);                                                           \
    _Pragma("unroll")                                                         \
    for (int r = 0; r < 4; r++) {                                             \
        int c = r * 256 + tid;                                                \
        int row = c >> 3, p = c & 7;                                          \
        int fsw = (row & 3) | (((row >> 3) & 1) << 2);                        \
        __builtin_amdgcn_global_load_lds(                                     \
            GPTR(Kp + (size_t)(ktv * 128 + row) * 64 + (p ^ fsw) * 8),        \
            SPTR(Ks[BUF] + (r * 256 + w * 64) * 8), 16, 0, 0);                \
    }                                                                         \
    _Pragma("unroll")                                                         \
    for (int r = 0; r < 4; r++) {                                             \
        int c = r * 256 + tid;                                                \
        int row = c >> 4, p = c & 15;                                         \
        __builtin_amdgcn_global_load_lds(                                     \
            GPTR(Vt + (size_t)row * L_ + ktv * 128 + (p ^ (row & 15)) * 8),   \
            SPTR(Vs[BUF] + (r * 256 + w * 64) * 8), 16, 0, 0);                \
    }                                                                         \
} while (0)

#define ATTN_TILE(BUF, KT, QF, QLANE, MVAR, LVAR, OACC, MASK) do {            \
    f32x4 p8[8] = {};                                                         \
    _Pragma("unroll")                                                         \
    for (int s = 0; s < 2; s++) {                                             \
        bf16x8 kf[8];                                                         \
        _Pragma("unroll")                                                     \
        for (int j = 0; j < 8; j++) {                                         \
            int row = (j >> 1) * 32 + (cl >> 2) * 8 + (j & 1) * 4 + (cl & 3); \
            int fsw = (row & 3) | (((row >> 3) & 1) << 2);                    \
            int ch = s * 4 + g;                                               \
            kf[j] = *(const bf16x8*)(Ks[BUF] + row * 64 + ((ch ^ fsw) * 8));  \
        }                                                                     \
        __builtin_amdgcn_s_setprio(1);                                        \
        _Pragma("unroll")                                                     \
        for (int j = 0; j < 8; j++)                                           \
            p8[j] = __builtin_amdgcn_mfma_f32_16x16x32_bf16(                  \
                kf[j], QF[s], p8[j], 0, 0, 0);                                \
        __builtin_amdgcn_s_setprio(0);                                        \
    }                                                                         \
    float mx0 = -__builtin_inff(), mx1 = -__builtin_inff();                   \
    float mx2 = -__builtin_inff(), mx3 = -__builtin_inff();                   \
    _Pragma("unroll")                                                         \
    for (int j = 0; j < 8; j++) {                                             \
        float v0 = p8[j][0], v1 = p8[j][1], v2 = p8[j][2], v3 = p8[j][3];     \
        if (MASK) {                                                           \
            int ka = (KT) * 128 + (j >> 1) * 32 + g * 8 + ((j & 1) << 2);     \
            v0 = (ka + 0 > (QLANE)) ? -__builtin_inff() : v0;                 \
            v1 = (ka + 1 > (QLANE)) ? -__builtin_inff() : v1;                 \
            v2 = (ka + 2 > (QLANE)) ? -__builtin_inff() : v2;                 \
            v3 = (ka + 3 > (QLANE)) ? -__builtin_inff() : v3;                 \
            p8[j][0] = v0; p8[j][1] = v1; p8[j][2] = v2; p8[j][3] = v3;       \
        }                                                                     \
        mx0 = fmaxf(mx0, v0); mx1 = fmaxf(mx1, v1);                           \
        mx2 = fmaxf(mx2, v2); mx3 = fmaxf(mx3, v3);                           \
    }                                                                         \
    float mx = fmaxf(fmaxf(mx0, mx1), fmaxf(mx2, mx3));                       \
    mx = fmaxf(mx, __shfl_xor(mx, 16));                                       \
    mx = fmaxf(mx, __shfl_xor(mx, 32));                                       \
    if (!__all(mx - MVAR <= 8.f)) {                                           \
        float mnew = fmaxf(MVAR, mx);                                         \
        float alpha = __builtin_amdgcn_exp2f(MVAR - mnew);                    \
        MVAR = mnew;                                                          \
        LVAR *= alpha;                                                        \
        _Pragma("unroll")                                                     \
        for (int r = 0; r < 4; r++) {                                         \
            float ar = __shfl(alpha, g * 4 + r);                              \
            _Pragma("unroll")                                                 \
            for (int dj = 0; dj < 4; dj++) OACC[dj][r] *= ar;                 \
        }                                                                     \
    }                                                                         \
    float s0 = 0.f, s1 = 0.f, s2 = 0.f, s3 = 0.f;                             \
    _Pragma("unroll")                                                         \
    for (int j = 0; j < 8; j++) {                                             \
        float e0 = __builtin_amdgcn_exp2f(p8[j][0] - MVAR);                   \
        float e1 = __builtin_amdgcn_exp2f(p8[j][1] - MVAR);                   \
        float e2 = __builtin_amdgcn_exp2f(p8[j][2] - MVAR);                   \
        float e3 = __builtin_amdgcn_exp2f(p8[j][3] - MVAR);                   \
        p8[j][0] = e0; p8[j][1] = e1; p8[j][2] = e2; p8[j][3] = e3;           \
        s0 += e0; s1 += e1; s2 += e2; s3 += e3;                               \
    }                                                                         \
    float ls = (s0 + s1) + (s2 + s3);                                         \
    ls += __shfl_xor(ls, 16);                                                 \
    ls += __shfl_xor(ls, 32);                                                 \
    LVAR += ls;                                                               \
    _Pragma("unroll")                                                         \
    for (int ks = 0; ks < 4; ks++) {                                          \
        bf16x8 pf;                                                            \
        _Pragma("unroll")                                                     \
        for (int e = 0; e < 8; e++)                                           \
            pf[e] = (__bf16)p8[2 * ks + (e >> 2)][e & 3];                     \
        bf16x8 vf[4];                                                         \
        _Pragma("unroll")                                                     \
        for (int dj = 0; dj < 4; dj++) {                                      \
            int vrow = dj * 16 + cl;                                          \
            int ch = ks * 4 + g;                                              \
            vf[dj] = *(const bf16x8*)(Vs[BUF] + vrow * 128 + ((ch ^ (vrow & 15)) * 8)); \
        }                                                                     \
        __builtin_amdgcn_s_setprio(1);                                        \
        _Pragma("unroll")                                                     \
        for (int dj = 0; dj < 4; dj++)                                        \
            OACC[dj] = __builtin_amdgcn_mfma_f32_16x16x32_bf16(               \
                pf, vf[dj], OACC[dj], 0, 0, 0);                               \
        __builtin_amdgcn_s_setprio(0);                                        \
    }                                                                         \
} while (0)

__global__ __launch_bounds__(256, 2) void attn_fwd(
        const bhalf* __restrict__ Qb, const bhalf* __restrict__ Kb,
        const bhalf* __restrict__ Vtb, bhalf* __restrict__ Ob) {
    __shared__ bhalf Ks[2][128 * 64];
    __shared__ bhalf Vs[2][64 * 128];

    const int bid  = blockIdx.x;
    const int xcd  = bid & 7, slot = bid >> 3;
    const int bx   = slot & 15;
    const int bh   = xcd + 8 * (slot >> 4);
    const int qbA  = 31 - bx;
    const int qbB  = bx;

    const int tid = threadIdx.x;
    const int w = tid >> 6, lane = tid & 63;
    const int g = lane >> 4, cl = lane & 15;

    const bhalf* Q  = Qb  + (size_t)bh * L_ * DH_;
    const bhalf* Kp = Kb  + (size_t)bh * L_ * DH_;
    const bhalf* Vt = Vtb + (size_t)bh * DH_ * L_;

    const int q0A = qbA * 64 + w * 16, qlA = q0A + cl;
    const int q0B = qbB * 64 + w * 16, qlB = q0B + cl;

    bf16x8 qfA[2], qfB[2];
#pragma unroll
    for (int s = 0; s < 2; s++) {
        qfA[s] = *(const bf16x8*)(Q + (size_t)(q0A + cl) * 64 + s * 32 + g * 8);
        qfB[s] = *(const bf16x8*)(Q + (size_t)(q0B + cl) * 64 + s * 32 + g * 8);
    }

    f32x4 oA[4] = {}, oB[4] = {};
    float mA = -__builtin_inff(), lA = 0.f;
    float mB = -__builtin_inff(), lB = 0.f;

    const int nktA = (qbA >> 1) + 1;
    const int nktB = (qbB >> 1) + 1;

    STAGE(0, 0);
    __syncthreads();

    for (int kt = 0; kt < nktA; ++kt) {
        int cur = kt & 1;
        if (kt + 1 < nktA) STAGE(cur ^ 1, kt + 1);
        if (kt < nktB) {
            ATTN_TILE(cur, kt, qfB, qlB, mB, lB, oB, (kt == nktB - 1));
        }
        ATTN_TILE(cur, kt, qfA, qlA, mA, lA, oA, (kt == nktA - 1));
        __syncthreads();
    }

    const int b = bh >> 4, h = bh & 15;
#pragma unroll
    for (int r = 0; r < 4; r++) {
        float lrA = __shfl(lA, g * 4 + r);
        float lrB = __shfl(lB, g * 4 + r);
        float invA = 1.f / (lrA + 1e-6f);
        float invB = 1.f / (lrB + 1e-6f);
        int qrA = q0A + g * 4 + r, qrB = q0B + g * 4 + r;
#pragma unroll
        for (int dj = 0; dj < 4; dj++) {
            Ob[((size_t)b * L_ + qrA) * D_ + h * 64 + dj * 16 + cl] =
                f2bf(oA[dj][r] * invA);
            Ob[((size_t)b * L_ + qrB) * D_ + h * 64 + dj * 16 + cl] =
                f2bf(oB[dj][r] * invB);
        }
    }
}

// ---------------------------------------------------------------------------
extern "C" void kernel_launch(void* const* d_in, const int* in_sizes, int n_in,
                              void* d_out, int out_size, void* d_ws, size_t ws_size,
                              hipStream_t stream) {
    const void* x     = d_in[0];   // [B,L,D]     f32 or bf16
    const void* Wqkv  = d_in[1];   // [D, 3D]
    const void* bqkv  = d_in[2];   // [3D]
    const void* Wproj = d_in[3];   // [D, D]
    const void* bproj = d_in[4];   // [D]

    char* ws = (char*)d_ws;
    const size_t SZ_FLG = 256;
    const size_t SZ_WQT = (size_t)3 * D_ * D_ * 2;        //  6 MB
    const size_t SZ_WPT = (size_t)D_ * D_ * 2;            //  2 MB
    const size_t SZ_X   = (size_t)B_ * L_ * D_ * 2;       //  8 MB
    const size_t SZ_BUF = (size_t)B_ * H_ * L_ * DH_ * 2; //  8 MB each

    int*   flag = (int*)ws;
    bhalf* Wq_t = (bhalf*)(ws + SZ_FLG);
    bhalf* Wp_t = (bhalf*)(ws + SZ_FLG + SZ_WQT);
    bhalf* Xb   = (bhalf*)(ws + SZ_FLG + SZ_WQT + SZ_WPT);
    bhalf* Qbuf = (bhalf*)(ws + SZ_FLG + SZ_WQT + SZ_WPT + SZ_X);
    bhalf* Kbuf = (bhalf*)(ws + SZ_FLG + SZ_WQT + SZ_WPT + SZ_X + SZ_BUF);
    bhalf* Vtbf = (bhalf*)(ws + SZ_FLG + SZ_WQT + SZ_WPT + SZ_X + 2 * SZ_BUF);
    bhalf* Obuf = (bhalf*)(ws + SZ_FLG + SZ_WQT + SZ_WPT + SZ_X + 3 * SZ_BUF);

    const int M = B_ * L_;   // 4096

    // 0. runtime dtype detection
    detect_dtype<<<1, 64, 0, stream>>>((const uint32*)x, flag);

    // 1. canonicalize inputs to bf16 workspace
    conv_bf16<<<2048, 256, 0, stream>>>(x, Xb, (B_ * L_ * D_) / 4, flag);
    tr_conv<<<dim3(3 * D_ / 32, D_ / 32), dim3(32, 8), 0, stream>>>(
        Wqkv, Wq_t, D_, 3 * D_, flag);
    tr_conv<<<dim3(D_ / 32, D_ / 32), dim3(32, 8), 0, stream>>>(
        Wproj, Wp_t, D_, D_, flag);

    // 2. QKV projection (phase-split 256x192 kernel, grid 16x16 = 1 block/CU)
    gemm_qkv256<<<dim3(3 * D_ / 192, M / 256), 512, 0, stream>>>(
        Xb, Wq_t, bqkv, Qbuf, Kbuf, Vtbf, D_, flag);

    // 3. causal flash attention -> Obuf [B,L,D] bf16
    attn_fwd<<<dim3(512), 256, 0, stream>>>(Qbuf, Kbuf, Vtbf, Obuf);

    // 4. output projection -> d_out
    gemm_proj<<<dim3(D_ / 128, M / 128), 256, 0, stream>>>(
        Obuf, Wp_t, bproj, d_out, M, D_, D_, flag);
}

// Round 13
// 129.605 us; speedup vs baseline: 1.1310x; 1.1285x over previous
//
#include <hip/hip_runtime.h>

// ---------------------------------------------------------------------------
// Fused causal MHA:  out = attn(x@Wqkv+b) @ Wproj + bproj
// B=2, L=2048, D=1024, H=16, DH=64
// Device buffers may be f32 or bf16 (runtime-detected); bf16 MFMA internally.
// Softmax in exp2 space (Q pre-scaled by 0.125*log2e in the QKV epilogue).
// ---------------------------------------------------------------------------

typedef __bf16 bf16x8 __attribute__((ext_vector_type(8)));
typedef float  f32x4  __attribute__((ext_vector_type(4)));
typedef unsigned short bhalf;
typedef unsigned int   uint32;

#define B_  2
#define L_  2048
#define D_  1024
#define H_  16
#define DH_ 64

#define GPTR(p) ((const __attribute__((address_space(1))) void*)(p))
#define SPTR(p) ((__attribute__((address_space(3))) void*)(p))

static __device__ __forceinline__ float bf2f(bhalf u) {
    union { uint32 u; float f; } x; x.u = ((uint32)u) << 16; return x.f;
}
static __device__ __forceinline__ bhalf f2bf(float f) {
    union { float f; uint32 u; } x; x.f = f;
    uint32 r = x.u + 0x7FFFu + ((x.u >> 16) & 1u);   // RNE
    return (bhalf)(r >> 16);
}

// ---------------------------------------------------------------------------
__global__ void detect_dtype(const uint32* __restrict__ xw, int* __restrict__ flag) {
    int t = threadIdx.x;                     // 64 threads
    uint32 w = xw[t];
    uint32 e = (w >> 7) & 0xFFu;             // exponent of low-half bf16
    int g = (e < 0x6Fu || e > 0x84u) ? 1 : 0;
#pragma unroll
    for (int off = 32; off; off >>= 1) g += __shfl_xor(g, off);
    if (t == 0) *flag = (g > 16) ? 0 : 1;
}

// ---------------------------------------------------------------------------
__global__ void conv_bf16(const void* __restrict__ in, bhalf* __restrict__ out,
                          int n4, const int* __restrict__ flag) {
    const bool isb = (*flag != 0);
    for (int i = blockIdx.x * blockDim.x + threadIdx.x; i < n4;
         i += gridDim.x * blockDim.x) {
        if (isb) {
            ((uint2*)out)[i] = ((const uint2*)in)[i];
        } else {
            float4 v = ((const float4*)in)[i];
            uint2 o;
            o.x = (uint32)f2bf(v.x) | ((uint32)f2bf(v.y) << 16);
            o.y = (uint32)f2bf(v.z) | ((uint32)f2bf(v.w) << 16);
            ((uint2*)out)[i] = o;
        }
    }
}

// ---------------------------------------------------------------------------
__global__ void tr_conv(const void* __restrict__ in, bhalf* __restrict__ out,
                        int R, int C, const int* __restrict__ flag) {
    __shared__ bhalf t[32][33];
    const bool isb = (*flag != 0);
    int bx = blockIdx.x, by = blockIdx.y;
    int tx = threadIdx.x, ty = threadIdx.y;   // (32, 8)
#pragma unroll
    for (int i = 0; i < 32; i += 8) {
        size_t idx = (size_t)(by * 32 + ty + i) * C + bx * 32 + tx;
        t[ty + i][tx] = isb ? ((const bhalf*)in)[idx]
                            : f2bf(((const float*)in)[idx]);
    }
    __syncthreads();
#pragma unroll
    for (int i = 0; i < 32; i += 8)
        out[(size_t)(bx * 32 + ty + i) * R + by * 32 + tx] = t[tx][ty + i];
}

// ---------------------------------------------------------------------------
// GEMM  C[M][N] = A[M][K] @ Bt[N][K]^T + bias[N]     (A, Bt are bf16)
// 128x128 tile, BK=32, 256 threads = 4 waves each 64x64.  (round-6 proven)
// Double-buffered LDS, prefetch-next-before-compute; one barrier per k-step.
// Chunk permutation pos = (c + row + (row>>2)) & 3 -> 2-way (free) LDS banks.
// MODE 0: write C row-major (f32 or bf16 per flag) to C0.
// MODE 1: QKV scatter: Q (pre-scaled by 0.125*log2e), K -> [B,H,L,DH] bf16,
//         V -> Vt [B,H,DH,L] bf16.
// ---------------------------------------------------------------------------

#define GSTAGE(BUF, KK) do {                                                  \
    int kko = (KK);                                                           \
    _Pragma("unroll")                                                         \
    for (int r = 0; r < 2; r++) {                                             \
        int c = r * 256 + tid;                                                \
        int row = c >> 2, p = c & 3;                                          \
        int gch = (p - row - (row >> 2)) & 3;                                 \
        __builtin_amdgcn_global_load_lds(                                     \
            GPTR(a0 + (size_t)row * K + kko + gch * 8),                       \
            SPTR(As[BUF] + (r * 256 + w * 64) * 8), 16, 0, 0);                \
        __builtin_amdgcn_global_load_lds(                                     \
            GPTR(b0 + (size_t)row * K + kko + gch * 8),                       \
            SPTR(Bs[BUF] + (r * 256 + w * 64) * 8), 16, 0, 0);                \
    }                                                                         \
} while (0)

template <int MODE>
__global__ __launch_bounds__(256) void gemm_bt(
        const bhalf* __restrict__ A, const bhalf* __restrict__ Bt,
        const void* __restrict__ bias,
        void* __restrict__ C0, bhalf* __restrict__ Qb,
        bhalf* __restrict__ Kb, bhalf* __restrict__ Vtb,
        int M, int N, int K, const int* __restrict__ flag) {
    __shared__ bhalf As[2][128 * 32];
    __shared__ bhalf Bs[2][128 * 32];
    const bool isb = (*flag != 0);
    const int tid  = threadIdx.x;
    const int w    = tid >> 6, lane = tid & 63;
    const int g    = lane >> 4, cl = lane & 15;
    const int m0   = blockIdx.y * 128, n0 = blockIdx.x * 128;
    const int wr   = (w >> 1) * 64, wc = (w & 1) * 64;

    f32x4 acc[4][4] = {};

    const bhalf* a0 = A  + (size_t)m0 * K;
    const bhalf* b0 = Bt + (size_t)n0 * K;

    GSTAGE(0, 0);
    __syncthreads();

    const int nk = K >> 5;
    for (int t = 0; t < nk; ++t) {
        int cur = t & 1;
        if (t + 1 < nk) GSTAGE(cur ^ 1, (t + 1) << 5);   // prefetch next tile

        bf16x8 af[4], bf4[4];
#pragma unroll
        for (int i = 0; i < 4; i++) {
            int ra = wr + i * 16 + cl;
            af[i]  = *(const bf16x8*)(As[cur] + ra * 32 +
                                      (((g + ra + (ra >> 2)) & 3) * 8));
            int rb = wc + i * 16 + cl;
            bf4[i] = *(const bf16x8*)(Bs[cur] + rb * 32 +
                                      (((g + rb + (rb >> 2)) & 3) * 8));
        }
        __builtin_amdgcn_s_setprio(1);
#pragma unroll
        for (int i = 0; i < 4; i++)
#pragma unroll
            for (int j = 0; j < 4; j++)
                acc[i][j] = __builtin_amdgcn_mfma_f32_16x16x32_bf16(
                    af[i], bf4[j], acc[i][j], 0, 0, 0);
        __builtin_amdgcn_s_setprio(0);

        __syncthreads();   // next buffer staged; cur free to overwrite
    }

    // epilogue: C/D layout col = lane&15, row = (lane>>4)*4 + reg
#pragma unroll
    for (int i = 0; i < 4; i++) {
#pragma unroll
        for (int j = 0; j < 4; j++) {
            int nn = n0 + wc + j * 16 + cl;
            float bv = isb ? bf2f(((const bhalf*)bias)[nn])
                           : ((const float*)bias)[nn];
#pragma unroll
            for (int r = 0; r < 4; r++) {
                int mm = m0 + wr + i * 16 + g * 4 + r;
                float v = acc[i][j][r] + bv;
                if (MODE == 0) {
                    if (isb) ((bhalf*)C0)[(size_t)mm * N + nn] = f2bf(v);
                    else     ((float*)C0)[(size_t)mm * N + nn] = v;
                } else {
                    int b = mm >> 11, l = mm & 2047;
                    int three = nn >> 10, rem = nn & 1023;
                    int h = rem >> 6, dh = rem & 63;
                    size_t bh = (size_t)(b * 16 + h);
                    if (three == 0) {
                        // fold SCALE * log2(e) into Q (softmax in exp2 space)
                        Qb[(bh * 2048 + l) * 64 + dh] = f2bf(v * 0.18033688f);
                    } else if (three == 1) {
                        Kb [(bh * 2048 + l) * 64 + dh] = f2bf(v);
                    } else {
                        Vtb[(bh * 64 + dh) * 2048 + l] = f2bf(v);
                    }
                }
            }
        }
    }
}

// ---------------------------------------------------------------------------
// Causal flash attention, swapped-QK^T / in-register exp2-space softmax.
// KVBLK=64: LDS 32 KB (dbuf K[64][64] + V[64][64]) -> 5 blocks/CU capacity.
// Grid 1024 blocks (one 64-row q-tile each, nkt = qb+1), ~4 resident/CU =
// 16 waves/CU (2x round-8's 8). Static balance: v=slot&31, grp=slot>>5,
// qb = grp&1 ? v : 31-v, bh = (bid&7) + 8*grp -- a CU taking the four
// same-v blocks (sequential within-XCD assignment) gets nkt sum == 66.
// Q [B,H,L,DH], K [B,H,L,DH], Vt [B,H,DH,L]; O -> [B,L,D] bf16.
// ---------------------------------------------------------------------------

// stage K/V 64-row tile kt into LDS buffer BUF (pre-swizzled global source)
#define STAGE(BUF, KT) do {                                                   \
    int ktv = (KT);                                                           \
    _Pragma("unroll")                                                         \
    for (int r = 0; r < 2; r++) {                                             \
        int c = r * 256 + tid;                                                \
        int row = c >> 3, p = c & 7;                                          \
        int fsw = (row & 3) | (((row >> 3) & 1) << 2);                        \
        __builtin_amdgcn_global_load_lds(                                     \
            GPTR(Kp + (size_t)(ktv * 64 + row) * 64 + (p ^ fsw) * 8),         \
            SPTR(Ks[BUF] + (r * 256 + w * 64) * 8), 16, 0, 0);                \
    }                                                                         \
    _Pragma("unroll")                                                         \
    for (int r = 0; r < 2; r++) {                                             \
        int c = r * 256 + tid;                                                \
        int row = c >> 3, p = c & 7;                                          \
        __builtin_amdgcn_global_load_lds(                                     \
            GPTR(Vt + (size_t)row * L_ + ktv * 64 + (p ^ (row & 7)) * 8),     \
            SPTR(Vs[BUF] + (r * 256 + w * 64) * 8), 16, 0, 0);                \
    }                                                                         \
} while (0)

// one 64-k tile: S^T = K@Q^T -> exp2 online softmax -> O += P@Vt^T
#define ATTN_TILE(BUF, KT, QF, QLANE, MVAR, LVAR, OACC, MASK) do {            \
    f32x4 p8[4] = {};                                                         \
    _Pragma("unroll")                                                         \
    for (int s = 0; s < 2; s++) {                                             \
        bf16x8 kf[4];                                                         \
        _Pragma("unroll")                                                     \
        for (int j = 0; j < 4; j++) {                                         \
            int row = (j >> 1) * 32 + (cl >> 2) * 8 + (j & 1) * 4 + (cl & 3); \
            int fsw = (row & 3) | (((row >> 3) & 1) << 2);                    \
            int ch = s * 4 + g;                                               \
            kf[j] = *(const bf16x8*)(Ks[BUF] + row * 64 + ((ch ^ fsw) * 8));  \
        }                                                                     \
        __builtin_amdgcn_s_setprio(1);                                        \
        _Pragma("unroll")                                                     \
        for (int j = 0; j < 4; j++)                                           \
            p8[j] = __builtin_amdgcn_mfma_f32_16x16x32_bf16(                  \
                kf[j], QF[s], p8[j], 0, 0, 0);                                \
        __builtin_amdgcn_s_setprio(0);                                        \
    }                                                                         \
    float mx0 = -__builtin_inff(), mx1 = -__builtin_inff();                   \
    float mx2 = -__builtin_inff(), mx3 = -__builtin_inff();                   \
    _Pragma("unroll")                                                         \
    for (int j = 0; j < 4; j++) {                                             \
        float v0 = p8[j][0], v1 = p8[j][1], v2 = p8[j][2], v3 = p8[j][3];     \
        if (MASK) {                                                           \
            int ka = (KT) * 64 + (j >> 1) * 32 + g * 8 + ((j & 1) << 2);      \
            v0 = (ka + 0 > (QLANE)) ? -__builtin_inff() : v0;                 \
            v1 = (ka + 1 > (QLANE)) ? -__builtin_inff() : v1;                 \
            v2 = (ka + 2 > (QLANE)) ? -__builtin_inff() : v2;                 \
            v3 = (ka + 3 > (QLANE)) ? -__builtin_inff() : v3;                 \
            p8[j][0] = v0; p8[j][1] = v1; p8[j][2] = v2; p8[j][3] = v3;       \
        }                                                                     \
        mx0 = fmaxf(mx0, v0); mx1 = fmaxf(mx1, v1);                           \
        mx2 = fmaxf(mx2, v2); mx3 = fmaxf(mx3, v3);                           \
    }                                                                         \
    float mx = fmaxf(fmaxf(mx0, mx1), fmaxf(mx2, mx3));                       \
    mx = fmaxf(mx, __shfl_xor(mx, 16));                                       \
    mx = fmaxf(mx, __shfl_xor(mx, 32));                                       \
    if (!__all(mx - MVAR <= 8.f)) {      /* defer-max */                      \
        float mnew = fmaxf(MVAR, mx);                                         \
        float alpha = __builtin_amdgcn_exp2f(MVAR - mnew);                    \
        MVAR = mnew;                                                          \
        LVAR *= alpha;                                                        \
        _Pragma("unroll")                                                     \
        for (int r = 0; r < 4; r++) {                                         \
            float ar = __shfl(alpha, g * 4 + r);                              \
            _Pragma("unroll")                                                 \
            for (int dj = 0; dj < 4; dj++) OACC[dj][r] *= ar;                 \
        }                                                                     \
    }                                                                         \
    float s0 = 0.f, s1 = 0.f, s2 = 0.f, s3 = 0.f;                             \
    _Pragma("unroll")                                                         \
    for (int j = 0; j < 4; j++) {                                             \
        float e0 = __builtin_amdgcn_exp2f(p8[j][0] - MVAR);                   \
        float e1 = __builtin_amdgcn_exp2f(p8[j][1] - MVAR);                   \
        float e2 = __builtin_amdgcn_exp2f(p8[j][2] - MVAR);                   \
        float e3 = __builtin_amdgcn_exp2f(p8[j][3] - MVAR);                   \
        p8[j][0] = e0; p8[j][1] = e1; p8[j][2] = e2; p8[j][3] = e3;           \
        s0 += e0; s1 += e1; s2 += e2; s3 += e3;                               \
    }                                                                         \
    float ls = (s0 + s1) + (s2 + s3);                                         \
    ls += __shfl_xor(ls, 16);                                                 \
    ls += __shfl_xor(ls, 32);                                                 \
    LVAR += ls;                                                               \
    _Pragma("unroll")                                                         \
    for (int ks = 0; ks < 2; ks++) {                                          \
        bf16x8 pf;                                                            \
        _Pragma("unroll")                                                     \
        for (int e = 0; e < 8; e++)                                           \
            pf[e] = (__bf16)p8[2 * ks + (e >> 2)][e & 3];                     \
        bf16x8 vf[4];                                                         \
        _Pragma("unroll")                                                     \
        for (int dj = 0; dj < 4; dj++) {                                      \
            int vrow = dj * 16 + cl;                                          \
            int ch = ks * 4 + g;                                              \
            vf[dj] = *(const bf16x8*)(Vs[BUF] + vrow * 64 + ((ch ^ (vrow & 7)) * 8)); \
        }                                                                     \
        __builtin_amdgcn_s_setprio(1);                                        \
        _Pragma("unroll")                                                     \
        for (int dj = 0; dj < 4; dj++)                                        \
            OACC[dj] = __builtin_amdgcn_mfma_f32_16x16x32_bf16(               \
                pf, vf[dj], OACC[dj], 0, 0, 0);                               \
        __builtin_amdgcn_s_setprio(0);                                        \
    }                                                                         \
} while (0)

__global__ __launch_bounds__(256, 4) void attn_fwd(
        const bhalf* __restrict__ Qb, const bhalf* __restrict__ Kb,
        const bhalf* __restrict__ Vtb, bhalf* __restrict__ Ob) {
    __shared__ bhalf Ks[2][64 * 64];   // [buf][krow][d]  swz (row&3)|(((row>>3)&1)<<2)
    __shared__ bhalf Vs[2][64 * 64];   // [buf][d][kcol]  swz row&7

    const int bid  = blockIdx.x;              // 0..1023
    const int xcd  = bid & 7, slot = bid >> 3;
    const int v    = slot & 31, grp = slot >> 5;     // v: 0..31, grp: 0..3
    const int qb   = (grp & 1) ? v : (31 - v);       // balanced across grp
    const int bh   = xcd + 8 * grp;                  // same-bh on one XCD

    const int tid = threadIdx.x;
    const int w = tid >> 6, lane = tid & 63;
    const int g = lane >> 4, cl = lane & 15;

    const bhalf* Q  = Qb  + (size_t)bh * L_ * DH_;
    const bhalf* Kp = Kb  + (size_t)bh * L_ * DH_;
    const bhalf* Vt = Vtb + (size_t)bh * DH_ * L_;

    const int q0 = qb * 64 + w * 16;          // wave's first q-row
    const int ql = q0 + cl;                   // this lane's softmax row

    bf16x8 qf[2];
#pragma unroll
    for (int s = 0; s < 2; s++)
        qf[s] = *(const bf16x8*)(Q + (size_t)(q0 + cl) * 64 + s * 32 + g * 8);

    f32x4 oacc[4] = {};
    float m = -__builtin_inff(), l = 0.f;

    const int nkt = qb + 1;                   // 64-wide k-tiles

    STAGE(0, 0);
    __syncthreads();

    for (int kt = 0; kt < nkt; ++kt) {
        int cur = kt & 1;
        if (kt + 1 < nkt) STAGE(cur ^ 1, kt + 1);   // prefetch next tile
        ATTN_TILE(cur, kt, qf, ql, m, l, oacc, (kt == nkt - 1));
        __syncthreads();   // next buffer staged; current free to overwrite
    }

    // epilogue: divide by denom (+1e-6 per reference), write O [B,L,D]
    const int b = bh >> 4, h = bh & 15;
#pragma unroll
    for (int r = 0; r < 4; r++) {
        float lr  = __shfl(l, g * 4 + r);
        float inv = 1.f / (lr + 1e-6f);
        int qrow = q0 + g * 4 + r;
#pragma unroll
        for (int dj = 0; dj < 4; dj++)
            Ob[((size_t)b * L_ + qrow) * D_ + h * 64 + dj * 16 + cl] =
                f2bf(oacc[dj][r] * inv);
    }
}

// ---------------------------------------------------------------------------
extern "C" void kernel_launch(void* const* d_in, const int* in_sizes, int n_in,
                              void* d_out, int out_size, void* d_ws, size_t ws_size,
                              hipStream_t stream) {
    const void* x     = d_in[0];   // [B,L,D]     f32 or bf16
    const void* Wqkv  = d_in[1];   // [D, 3D]
    const void* bqkv  = d_in[2];   // [3D]
    const void* Wproj = d_in[3];   // [D, D]
    const void* bproj = d_in[4];   // [D]

    char* ws = (char*)d_ws;
    const size_t SZ_FLG = 256;
    const size_t SZ_WQT = (size_t)3 * D_ * D_ * 2;        //  6 MB
    const size_t SZ_WPT = (size_t)D_ * D_ * 2;            //  2 MB
    const size_t SZ_X   = (size_t)B_ * L_ * D_ * 2;       //  8 MB
    const size_t SZ_BUF = (size_t)B_ * H_ * L_ * DH_ * 2; //  8 MB each

    int*   flag = (int*)ws;
    bhalf* Wq_t = (bhalf*)(ws + SZ_FLG);
    bhalf* Wp_t = (bhalf*)(ws + SZ_FLG + SZ_WQT);
    bhalf* Xb   = (bhalf*)(ws + SZ_FLG + SZ_WQT + SZ_WPT);
    bhalf* Qbuf = (bhalf*)(ws + SZ_FLG + SZ_WQT + SZ_WPT + SZ_X);
    bhalf* Kbuf = (bhalf*)(ws + SZ_FLG + SZ_WQT + SZ_WPT + SZ_X + SZ_BUF);
    bhalf* Vtbf = (bhalf*)(ws + SZ_FLG + SZ_WQT + SZ_WPT + SZ_X + 2 * SZ_BUF);
    bhalf* Obuf = (bhalf*)(ws + SZ_FLG + SZ_WQT + SZ_WPT + SZ_X + 3 * SZ_BUF);

    const int M = B_ * L_;   // 4096

    // 0. runtime dtype detection
    detect_dtype<<<1, 64, 0, stream>>>((const uint32*)x, flag);

    // 1. canonicalize inputs to bf16 workspace
    conv_bf16<<<2048, 256, 0, stream>>>(x, Xb, (B_ * L_ * D_) / 4, flag);
    tr_conv<<<dim3(3 * D_ / 32, D_ / 32), dim3(32, 8), 0, stream>>>(
        Wqkv, Wq_t, D_, 3 * D_, flag);
    tr_conv<<<dim3(D_ / 32, D_ / 32), dim3(32, 8), 0, stream>>>(
        Wproj, Wp_t, D_, D_, flag);

    // 2. QKV projection + scatter to Q (pre-scaled), K [B,H,L,DH], Vt [B,H,DH,L]
    gemm_bt<1><<<dim3(3 * D_ / 128, M / 128), 256, 0, stream>>>(
        Xb, Wq_t, bqkv, nullptr, Qbuf, Kbuf, Vtbf, M, 3 * D_, D_, flag);

    // 3. causal flash attention -> Obuf [B,L,D] bf16
    attn_fwd<<<dim3(1024), 256, 0, stream>>>(Qbuf, Kbuf, Vtbf, Obuf);

    // 4. output projection -> d_out
    gemm_bt<0><<<dim3(D_ / 128, M / 128), 256, 0, stream>>>(
        Obuf, Wp_t, bproj, d_out, nullptr, nullptr, nullptr, M, D_, D_, flag);
}